// Round 13
// baseline (381.318 us; speedup 1.0000x reference)
//
#include <hip/hip_runtime.h>
#include <hip/hip_bf16.h>

typedef _Float16 f16;
typedef f16 f16x8 __attribute__((ext_vector_type(8)));
typedef float f32x4 __attribute__((ext_vector_type(4)));

#define T_LEN 784
#define BATCH 64
#define DH 512
#define NCH (BATCH*DH)        // 32768 chains
#define M_ROWS (T_LEN*BATCH)  // 50176
#define NCHUNK 16
#define CLEN 49               // 784 = 16*49

#define ACT_SCALE (1.0f/256.0f)   // power-of-2 activation scaling: exact, keeps fp16 in range
#define ACT_INV   256.0f

// global -> LDS direct DMA, 16B per lane; dest = wave-uniform base + lane*16 (m104/m108)
#define GLL16(g, s)                                                             \
    __builtin_amdgcn_global_load_lds(                                           \
        (const __attribute__((address_space(1))) void*)(g),                     \
        (__attribute__((address_space(3))) void*)(s), 16, 0, 0)

#define VMCNT(n) asm volatile("s_waitcnt vmcnt(" #n ")" ::: "memory")

// ---------------- weight prep: fp32 [k][n] -> fp16 [n][k] (transpose+convert) ----------------
__global__ void prep_weights(const float* __restrict__ B, const float* __restrict__ C,
                             f16* __restrict__ Bt, f16* __restrict__ Ct) {
    __shared__ float tile[32][33];
    int z = blockIdx.z;  // 0..2: B layer z ; 3..5: C layer z-3
    const float* src = (z < 3) ? (B + (size_t)z * DH * DH) : (C + (size_t)(z - 3) * DH * DH);
    f16* dst = (z < 3) ? (Bt + (size_t)z * DH * DH) : (Ct + (size_t)(z - 3) * DH * DH);
    int tx = threadIdx.x, ty = threadIdx.y;  // 32 x 8
    int nb = blockIdx.x * 32, kb = blockIdx.y * 32;
#pragma unroll
    for (int i = 0; i < 4; i++) {
        int k = ty + i * 8;
        tile[k][tx] = src[(size_t)(kb + k) * DH + nb + tx];
    }
    __syncthreads();
#pragma unroll
    for (int i = 0; i < 4; i++) {
        int n = ty + i * 8;
        dst[(size_t)(nb + n) * DH + kb + tx] = (f16)tile[tx][n];
    }
}

// ---------------- first dense: H = relu(x @ W0 + b0) * ACT_SCALE, fp16 out ----------------
__global__ void dense0_kernel(const float* __restrict__ x, const float* __restrict__ W0,
                              const float* __restrict__ b0, f16* __restrict__ H) {
    int tid = blockIdx.x * 256 + threadIdx.x;
    int m = tid >> 6;
    int hb = (tid & 63) * 8;
    float x0 = x[(size_t)m * 2], x1 = x[(size_t)m * 2 + 1];
    f32x4 wa0 = *(const f32x4*)(W0 + hb);
    f32x4 wa1 = *(const f32x4*)(W0 + hb + 4);
    f32x4 wb0 = *(const f32x4*)(W0 + DH + hb);
    f32x4 wb1 = *(const f32x4*)(W0 + DH + hb + 4);
    f32x4 c0 = *(const f32x4*)(b0 + hb);
    f32x4 c1 = *(const f32x4*)(b0 + hb + 4);
    f16x8 o;
#pragma unroll
    for (int j = 0; j < 4; j++) {
        float v = fmaxf(fmaf(x0, wa0[j], fmaf(x1, wb0[j], c0[j])), 0.f) * ACT_SCALE;
        o[j] = (f16)v;
    }
#pragma unroll
    for (int j = 0; j < 4; j++) {
        float v = fmaxf(fmaf(x0, wa1[j], fmaf(x1, wb1[j], c1[j])), 0.f) * ACT_SCALE;
        o[4 + j] = (f16)v;
    }
    *(f16x8*)(H + (size_t)m * DH + hb) = o;
}

// ---------------- fp16 MFMA GEMM: Out[M,512] = A[M,512] @ Bt^T (Bt is [n][k]) ----------------
// R5 K-loop with ASYMMETRIC ring: A = 3 bufs / depth-2 (HBM-cold ~900cyc), B = 2 bufs /
// depth-1 (L2-resident 512KB panel, ~200-400cyc; 1-iter issue->wait gap covers it).
// LDS 48KB -> 40KB => 4 blocks/CU (16 waves) instead of 3: the R5-R12 plateau shows all
// pipes <50% busy with waves collectively idle -> TLP-limited, so +33% independent block
// pipelines is the lever. Issue order per iter: B(t+1) then A(t+2); VMCNT(2) leaves exactly
// A(t+1) in flight (oldest-first queue: ...A(t),B(t),A(t+1)). Tail uses VMCNT(0).
// XOR-swizzled k-slots (rule #21). s_setprio(1) around MFMA cluster (T5, free).
template <int RELU>
__global__ __launch_bounds__(256) void gemm_k(const f16* __restrict__ A,
                                              const f16* __restrict__ Bt,
                                              f16* __restrict__ Out) {
    __shared__ __align__(16) f16 As[3][128 * 32];
    __shared__ __align__(16) f16 Bs[2][128 * 32];
    const int tid = threadIdx.x;
    const int lane = tid & 63;
    const int wave = tid >> 6;
    const int wr = wave >> 1, wc = wave & 1;
    const size_t mb = (size_t)blockIdx.x * 128;
    const int nb = blockIdx.y * 128;

    // staging: wave w, round p covers rows [p*64 + w*16, +16); lane l -> row +(l>>2), slot l&3
    const int rl = lane >> 2, sl = lane & 3;
    const int ssl = sl ^ ((rl >> 1) & 3);             // pre-swizzled source k-slot
    const int rowS0 = wave * 16 + rl;                 // round 0 row
    const int rowS1 = 64 + wave * 16 + rl;            // round 1 row
    const f16* gA0 = A + (mb + rowS0) * DH + ssl * 8;
    const f16* gA1 = A + (mb + rowS1) * DH + ssl * 8;
    const f16* gB0 = Bt + (size_t)(nb + rowS0) * DH + ssl * 8;
    const f16* gB1 = Bt + (size_t)(nb + rowS1) * DH + ssl * 8;
    const int ldsOff0 = (wave * 16) * 32;             // wave-uniform LDS elem offsets
    const int ldsOff1 = (64 + wave * 16) * 32;

    // fragment read offsets: row = w*64 + i*16 + rA, k-slot kq swizzled by f(rA)
    const int rA = lane & 15, kq = lane >> 4;
    const int fsl = kq ^ ((rA >> 1) & 3);
    int offA[4], offB[4];
#pragma unroll
    for (int i = 0; i < 4; i++) offA[i] = (wr * 64 + i * 16 + rA) * 32 + fsl * 8;
#pragma unroll
    for (int j = 0; j < 4; j++) offB[j] = (wc * 64 + j * 16 + rA) * 32 + fsl * 8;

    f32x4 acc[4][4] = {};

#define STAGE_A(b, kt)                      \
    do {                                    \
        GLL16(gA0 + (kt), &As[b][ldsOff0]); \
        GLL16(gA1 + (kt), &As[b][ldsOff1]); \
    } while (0)
#define STAGE_B(b, kt)                      \
    do {                                    \
        GLL16(gB0 + (kt), &Bs[b][ldsOff0]); \
        GLL16(gB1 + (kt), &Bs[b][ldsOff1]); \
    } while (0)

#define COMPUTE(ba, bb)                                                                         \
    do {                                                                                        \
        f16x8 af[4], bg[4];                                                                     \
        _Pragma("unroll") for (int i = 0; i < 4; i++) af[i] = *(const f16x8*)&As[ba][offA[i]];  \
        _Pragma("unroll") for (int j = 0; j < 4; j++) bg[j] = *(const f16x8*)&Bs[bb][offB[j]];  \
        __builtin_amdgcn_s_setprio(1);                                                          \
        _Pragma("unroll") for (int i = 0; i < 4; i++)                                           \
        _Pragma("unroll") for (int j = 0; j < 4; j++)                                           \
            acc[i][j] = __builtin_amdgcn_mfma_f32_16x16x32_f16(af[i], bg[j], acc[i][j], 0, 0, 0); \
        __builtin_amdgcn_s_setprio(0);                                                          \
    } while (0)

    // prologue queue (oldest->newest): A(0), B(0), A(1)
    STAGE_A(0, 0);
    STAGE_B(0, 0);
    STAGE_A(1, 32);

    // iter t: wait A(t),B(t) landed (A(t+1) stays in flight), then issue B(t+1), A(t+2)
#pragma unroll
    for (int t = 0; t < 15; ++t) {
        VMCNT(2);
        __builtin_amdgcn_s_barrier();
        STAGE_B((t + 1) & 1, (t + 1) * 32);            // t<15 always here
        if (t < 14) STAGE_A((t + 2) % 3, (t + 2) * 32);
        COMPUTE(t % 3, t & 1);
    }
    VMCNT(0);
    __builtin_amdgcn_s_barrier();
    COMPUTE(15 % 3, 15 & 1);  // bufs A0, B1
#undef STAGE_A
#undef STAGE_B
#undef COMPUTE

    // epilogue: D frag layout col=lane&15, row=(lane>>4)*4+reg
    const int crow = (lane >> 4) * 4;
    const int ccol = lane & 15;
#pragma unroll
    for (int i = 0; i < 4; i++)
#pragma unroll
        for (int j = 0; j < 4; j++) {
#pragma unroll
            for (int r = 0; r < 4; r++) {
                size_t row = mb + wr * 64 + i * 16 + crow + r;
                int col = nb + wc * 64 + j * 16 + ccol;
                float v = acc[i][j][r];
                if (RELU) v = fmaxf(v, 0.f);
                Out[row * DH + col] = (f16)v;
            }
        }
}

// ---------------- chunked diagonal scan over T (h_t = a*h_{t-1} + u_t) ----------------
__global__ void scan_pass1(const f16* __restrict__ U, const float* __restrict__ Al,
                           float* __restrict__ finals) {
    int tid = blockIdx.x * 256 + threadIdx.x;  // 524288 threads
    int ch = tid & (NCH - 1);
    int c = tid >> 15;
    float a = Al[ch & (DH - 1)];
    const f16* p = U + (size_t)(c * CLEN) * NCH + ch;
    float h = 0.f;
#pragma unroll
    for (int i = 0; i < CLEN; i++) h = fmaf(h, a, (float)p[(size_t)i * NCH]);
    finals[(size_t)c * NCH + ch] = h;
}

// pass3 with pass2 merged (R12, verified): recompute chunk carry from `finals` in-thread.
__global__ void scan_pass3(f16* __restrict__ U, const float* __restrict__ Al,
                           const float* __restrict__ finals) {
    int tid = blockIdx.x * 256 + threadIdx.x;
    int ch = tid & (NCH - 1);
    int c = tid >> 15;
    float a = Al[ch & (DH - 1)];
    float a49 = 1.f;
#pragma unroll
    for (int i = 0; i < CLEN; i++) a49 *= a;
    float carry = 0.f;
    for (int cc = 0; cc < c; cc++)
        carry = fmaf(carry, a49, finals[(size_t)cc * NCH + ch]);
    f16* p = U + (size_t)(c * CLEN) * NCH + ch;
    float h = carry;
#pragma unroll
    for (int i = 0; i < CLEN; i++) {
        h = fmaf(h, a, (float)p[(size_t)i * NCH]);
        p[(size_t)i * NCH] = (f16)h;
    }
}

// ---------------- final dense: out[m,0:2] = (H[m,:] @ Wf) * ACT_INV + bf ----------------
__global__ void final_dense(const f16* __restrict__ H, const float* __restrict__ Wf,
                            const float* __restrict__ bf_, float* __restrict__ out) {
    __shared__ float WfS[DH * 2];
    for (int i = threadIdx.x; i < DH * 2; i += 256) WfS[i] = Wf[i];
    __syncthreads();
    int wave = threadIdx.x >> 6, lane = threadIdx.x & 63;
    size_t m = (size_t)blockIdx.x * 4 + wave;
    f16x8 v = *(const f16x8*)(H + m * DH + lane * 8);
    float d0 = 0.f, d1 = 0.f;
#pragma unroll
    for (int j = 0; j < 8; j++) {
        float hv = (float)v[j];
        int h = lane * 8 + j;
        d0 = fmaf(hv, WfS[h * 2], d0);
        d1 = fmaf(hv, WfS[h * 2 + 1], d1);
    }
#pragma unroll
    for (int off = 32; off; off >>= 1) {
        d0 += __shfl_down(d0, off);
        d1 += __shfl_down(d1, off);
    }
    if (lane == 0) {
        out[m * 2] = fmaf(d0, ACT_INV, bf_[0]);
        out[m * 2 + 1] = fmaf(d1, ACT_INV, bf_[1]);
    }
}

extern "C" void kernel_launch(void* const* d_in, const int* in_sizes, int n_in,
                              void* d_out, int out_size, void* d_ws, size_t ws_size,
                              hipStream_t stream) {
    (void)in_sizes; (void)n_in; (void)out_size; (void)ws_size;
    const float* x   = (const float*)d_in[0];
    const float* W0  = (const float*)d_in[1];
    const float* b0  = (const float*)d_in[2];
    const float* A   = (const float*)d_in[3];
    const float* Bw  = (const float*)d_in[4];
    const float* Cw  = (const float*)d_in[5];
    const float* Wf  = (const float*)d_in[6];
    const float* bfv = (const float*)d_in[7];
    float* out = (float*)d_out;

    char* ws = (char*)d_ws;
    size_t off = 0;
    auto alloc = [&](size_t bytes) {
        void* p = ws + off;
        off += (bytes + 255) & ~(size_t)255;
        return p;
    };
    f16* Bt = (f16*)alloc((size_t)3 * DH * DH * 2);
    f16* Ct = (f16*)alloc((size_t)3 * DH * DH * 2);
    f16* P  = (f16*)alloc((size_t)M_ROWS * DH * 2);  // layer activations
    f16* Q  = (f16*)alloc((size_t)M_ROWS * DH * 2);  // u / hs buffer
    float* finals  = (float*)alloc((size_t)NCH * NCHUNK * 4);

    dim3 b256(256);
    prep_weights<<<dim3(16, 16, 6), dim3(32, 8), 0, stream>>>(Bw, Cw, Bt, Ct);
    dense0_kernel<<<M_ROWS * 64 / 256, b256, 0, stream>>>(x, W0, b0, P);
    for (int l = 0; l < 3; l++) {
        const float* Al = A + l * DH;
        gemm_k<0><<<dim3(M_ROWS / 128, 4), b256, 0, stream>>>(P, Bt + (size_t)l * DH * DH, Q);
        scan_pass1<<<NCH * NCHUNK / 256, b256, 0, stream>>>(Q, Al, finals);
        scan_pass3<<<NCH * NCHUNK / 256, b256, 0, stream>>>(Q, Al, finals);
        gemm_k<1><<<dim3(M_ROWS / 128, 4), b256, 0, stream>>>(Q, Ct + (size_t)l * DH * DH, P);
    }
    final_dense<<<M_ROWS / 4, b256, 0, stream>>>(P, Wf, bfv, out);
}

// Round 14
// 365.314 us; speedup vs baseline: 1.0438x; 1.0438x over previous
//
#include <hip/hip_runtime.h>
#include <hip/hip_bf16.h>

typedef _Float16 f16;
typedef f16 f16x8 __attribute__((ext_vector_type(8)));
typedef float f32x4 __attribute__((ext_vector_type(4)));

#define T_LEN 784
#define BATCH 64
#define DH 512
#define NCH (BATCH*DH)        // 32768 chains
#define M_ROWS (T_LEN*BATCH)  // 50176
#define NCHUNK 16
#define CLEN 49               // 784 = 16*49

#define ACT_SCALE (1.0f/256.0f)   // power-of-2 activation scaling: exact, keeps fp16 in range
#define ACT_INV   256.0f

// global -> LDS direct DMA, 16B per lane; dest = wave-uniform base + lane*16 (m104/m108)
#define GLL16(g, s)                                                             \
    __builtin_amdgcn_global_load_lds(                                           \
        (const __attribute__((address_space(1))) void*)(g),                     \
        (__attribute__((address_space(3))) void*)(s), 16, 0, 0)

#define VMCNT(n) asm volatile("s_waitcnt vmcnt(" #n ")" ::: "memory")
#define SBAR()   asm volatile("s_barrier" ::: "memory")

// ---------------- weight prep: fp32 [k][n] -> fp16 [n][k] (transpose+convert) ----------------
__global__ void prep_weights(const float* __restrict__ B, const float* __restrict__ C,
                             f16* __restrict__ Bt, f16* __restrict__ Ct) {
    __shared__ float tile[32][33];
    int z = blockIdx.z;  // 0..2: B layer z ; 3..5: C layer z-3
    const float* src = (z < 3) ? (B + (size_t)z * DH * DH) : (C + (size_t)(z - 3) * DH * DH);
    f16* dst = (z < 3) ? (Bt + (size_t)z * DH * DH) : (Ct + (size_t)(z - 3) * DH * DH);
    int tx = threadIdx.x, ty = threadIdx.y;  // 32 x 8
    int nb = blockIdx.x * 32, kb = blockIdx.y * 32;
#pragma unroll
    for (int i = 0; i < 4; i++) {
        int k = ty + i * 8;
        tile[k][tx] = src[(size_t)(kb + k) * DH + nb + tx];
    }
    __syncthreads();
#pragma unroll
    for (int i = 0; i < 4; i++) {
        int n = ty + i * 8;
        dst[(size_t)(nb + n) * DH + kb + tx] = (f16)tile[tx][n];
    }
}

// ---------------- first dense: H = relu(x @ W0 + b0) * ACT_SCALE, fp16 out ----------------
__global__ void dense0_kernel(const float* __restrict__ x, const float* __restrict__ W0,
                              const float* __restrict__ b0, f16* __restrict__ H) {
    int tid = blockIdx.x * 256 + threadIdx.x;
    int m = tid >> 6;
    int hb = (tid & 63) * 8;
    float x0 = x[(size_t)m * 2], x1 = x[(size_t)m * 2 + 1];
    f32x4 wa0 = *(const f32x4*)(W0 + hb);
    f32x4 wa1 = *(const f32x4*)(W0 + hb + 4);
    f32x4 wb0 = *(const f32x4*)(W0 + DH + hb);
    f32x4 wb1 = *(const f32x4*)(W0 + DH + hb + 4);
    f32x4 c0 = *(const f32x4*)(b0 + hb);
    f32x4 c1 = *(const f32x4*)(b0 + hb + 4);
    f16x8 o;
#pragma unroll
    for (int j = 0; j < 4; j++) {
        float v = fmaxf(fmaf(x0, wa0[j], fmaf(x1, wb0[j], c0[j])), 0.f) * ACT_SCALE;
        o[j] = (f16)v;
    }
#pragma unroll
    for (int j = 0; j < 4; j++) {
        float v = fmaxf(fmaf(x0, wa1[j], fmaf(x1, wb1[j], c1[j])), 0.f) * ACT_SCALE;
        o[4 + j] = (f16)v;
    }
    *(f16x8*)(H + (size_t)m * DH + hb) = o;
}

// ---------------- 8-phase fp16 MFMA GEMM: Out[M,512] = A[M,512] @ Bt^T ----------------
// 256x256 tile, BK=64, 8 waves (2M x 4N), 512 threads, grid (196,2). LDS = 4-slot
// half-tile rings (A: 4x[128][64], B same; 128KB). Wave output = 128x64 INTERLEAVED:
// phase q of K-tile kt computes rows q*64+wm*32 (+32) -> phase q reads only A-half q>>1,
// so A-half slots die progressively and the staging stream can overwrite dead slots.
// Schedule (hand-verified leads/WAR): prologue stages A0,A1,B0,B1,A2; at kt: q0:
// vmcnt(2)+barrier, stage A(2kt+3),B(2kt+2), load B-frags (held in regs for all 4
// phases); q1: stage B(2kt+3); q2: stage A(2kt+4). vmcnt(2) allows only the newest
// A-half in flight; every staged half has >=3 phases of lead; every slot overwrite
// happens after its last reader's barrier. XOR swizzle k8slot ^= row&7 (rule #21:
// linear LDS dest + pre-swizzled source + swizzled read; 2 lanes/bank on ds_read_b128).
template <int RELU>
__global__ __launch_bounds__(512, 2) void gemm8(const f16* __restrict__ A,
                                                const f16* __restrict__ Bt,
                                                f16* __restrict__ Out) {
    __shared__ __align__(16) f16 As[4][128 * 64];
    __shared__ __align__(16) f16 Bs[4][128 * 64];
    const int tid = threadIdx.x;
    const int lane = tid & 63;
    const int wave = tid >> 6;      // 0..7
    const int wm = wave >> 2;       // 0..1
    const int wn = wave & 3;        // 0..3
    const size_t mb = (size_t)blockIdx.x * 256;
    const int nb = blockIdx.y * 256;

    // staging: thread covers (row_in_half = r*64 + (tid>>3), k8slot = tid&7), rounds r=0,1
    const int srw = tid >> 3;                 // 0..63
    const int ss = (tid & 7) ^ (srw & 7);     // pre-swizzled source k8-slot (same both rounds)
    const int ldsR0 = (wave * 8) * 64;        // wave-uniform LDS elem offsets
    const int ldsR1 = (64 + wave * 8) * 64;

#define SA(H)                                                                                  \
    do {                                                                                       \
        GLL16(A + (mb + ((H) & 1) * 128 + srw) * DH + ((H) >> 1) * 64 + ss * 8,                \
              &As[(H) & 3][ldsR0]);                                                            \
        GLL16(A + (mb + ((H) & 1) * 128 + 64 + srw) * DH + ((H) >> 1) * 64 + ss * 8,           \
              &As[(H) & 3][ldsR1]);                                                            \
    } while (0)
#define SB(H)                                                                                  \
    do {                                                                                       \
        GLL16(Bt + ((size_t)nb + ((H) & 1) * 128 + srw) * DH + ((H) >> 1) * 64 + ss * 8,       \
              &Bs[(H) & 3][ldsR0]);                                                            \
        GLL16(Bt + ((size_t)nb + ((H) & 1) * 128 + 64 + srw) * DH + ((H) >> 1) * 64 + ss * 8,  \
              &Bs[(H) & 3][ldsR1]);                                                            \
    } while (0)

    // fragment read offsets (within a half-tile [row][64k]); k8 = (ks*4+kq) ^ (row&7)
    const int rA = lane & 15, kq = lane >> 4;
    int aoff[2][2], boff[4][2];
#pragma unroll
    for (int fr = 0; fr < 2; fr++)
#pragma unroll
        for (int ks = 0; ks < 2; ks++)
            aoff[fr][ks] = (fr * 16 + rA) * 64 + ((ks * 4 + kq) ^ (rA & 7)) * 8;
#pragma unroll
    for (int fc = 0; fc < 4; fc++)
#pragma unroll
        for (int ks = 0; ks < 2; ks++)
            boff[fc][ks] = ((wn & 1) * 64 + fc * 16 + rA) * 64 + ((ks * 4 + kq) ^ (rA & 7)) * 8;

    f32x4 acc[4][2][4] = {};   // [q][fr][fc]

    // prologue: 5 half-tiles in flight (10 loads/thread), order: A0 A1 B0 B1 A2
    SA(0); SA(1); SB(0); SB(1); SA(2);

#pragma unroll
    for (int kt = 0; kt < 8; ++kt) {
        f16x8 bg[4][2];
#pragma unroll
        for (int q = 0; q < 4; ++q) {
            if (q == 0) {
                if (kt < 7) { VMCNT(2); } else { VMCNT(0); }   // only newest A-half in flight
                SBAR();                                        // all waves' K-tile kt landed
                if (kt <= 6) { SA(2 * kt + 3); SB(2 * kt + 2); }
                const f16* pb = &Bs[(2 * kt + (wn >> 1)) & 3][0];
#pragma unroll
                for (int fc = 0; fc < 4; fc++)
#pragma unroll
                    for (int ks = 0; ks < 2; ks++)
                        bg[fc][ks] = *(const f16x8*)(pb + boff[fc][ks]);
            }
            if (q == 1 && kt <= 6) SB(2 * kt + 3);
            if (q == 2 && kt <= 5) SA(2 * kt + 4);
            const f16* pa = &As[(2 * kt + (q >> 1)) & 3][((q & 1) * 64 + wm * 32) * 64];
            f16x8 af[2][2];
#pragma unroll
            for (int fr = 0; fr < 2; fr++)
#pragma unroll
                for (int ks = 0; ks < 2; ks++)
                    af[fr][ks] = *(const f16x8*)(pa + aoff[fr][ks]);
            __builtin_amdgcn_s_setprio(1);
#pragma unroll
            for (int fr = 0; fr < 2; fr++)
#pragma unroll
                for (int fc = 0; fc < 4; fc++)
#pragma unroll
                    for (int ks = 0; ks < 2; ks++)
                        acc[q][fr][fc] = __builtin_amdgcn_mfma_f32_16x16x32_f16(
                            af[fr][ks], bg[fc][ks], acc[q][fr][fc], 0, 0, 0);
            __builtin_amdgcn_s_setprio(0);
            if (q < 3) SBAR();   // q=3's WAR is covered by next kt's q0 top barrier
        }
    }
#undef SA
#undef SB

    // epilogue: D frag layout col=lane&15, row=(lane>>4)*4+reg (verified R2-R12)
    const int crow = (lane >> 4) * 4;
    const int ccol = lane & 15;
#pragma unroll
    for (int q = 0; q < 4; ++q)
#pragma unroll
        for (int fr = 0; fr < 2; ++fr)
#pragma unroll
            for (int fc = 0; fc < 4; ++fc)
#pragma unroll
                for (int r = 0; r < 4; ++r) {
                    size_t row = mb + q * 64 + wm * 32 + fr * 16 + crow + r;
                    int col = nb + wn * 64 + fc * 16 + ccol;
                    float v = acc[q][fr][fc][r];
                    if (RELU) v = fmaxf(v, 0.f);
                    Out[row * DH + col] = (f16)v;
                }
}

// ---------------- chunked diagonal scan over T (h_t = a*h_{t-1} + u_t) ----------------
__global__ void scan_pass1(const f16* __restrict__ U, const float* __restrict__ Al,
                           float* __restrict__ finals) {
    int tid = blockIdx.x * 256 + threadIdx.x;  // 524288 threads
    int ch = tid & (NCH - 1);
    int c = tid >> 15;
    float a = Al[ch & (DH - 1)];
    const f16* p = U + (size_t)(c * CLEN) * NCH + ch;
    float h = 0.f;
#pragma unroll
    for (int i = 0; i < CLEN; i++) h = fmaf(h, a, (float)p[(size_t)i * NCH]);
    finals[(size_t)c * NCH + ch] = h;
}

// pass3 with pass2 merged (R12, verified): recompute chunk carry from `finals` in-thread.
__global__ void scan_pass3(f16* __restrict__ U, const float* __restrict__ Al,
                           const float* __restrict__ finals) {
    int tid = blockIdx.x * 256 + threadIdx.x;
    int ch = tid & (NCH - 1);
    int c = tid >> 15;
    float a = Al[ch & (DH - 1)];
    float a49 = 1.f;
#pragma unroll
    for (int i = 0; i < CLEN; i++) a49 *= a;
    float carry = 0.f;
    for (int cc = 0; cc < c; cc++)
        carry = fmaf(carry, a49, finals[(size_t)cc * NCH + ch]);
    f16* p = U + (size_t)(c * CLEN) * NCH + ch;
    float h = carry;
#pragma unroll
    for (int i = 0; i < CLEN; i++) {
        h = fmaf(h, a, (float)p[(size_t)i * NCH]);
        p[(size_t)i * NCH] = (f16)h;
    }
}

// ---------------- final dense: out[m,0:2] = (H[m,:] @ Wf) * ACT_INV + bf ----------------
__global__ void final_dense(const f16* __restrict__ H, const float* __restrict__ Wf,
                            const float* __restrict__ bf_, float* __restrict__ out) {
    __shared__ float WfS[DH * 2];
    for (int i = threadIdx.x; i < DH * 2; i += 256) WfS[i] = Wf[i];
    __syncthreads();
    int wave = threadIdx.x >> 6, lane = threadIdx.x & 63;
    size_t m = (size_t)blockIdx.x * 4 + wave;
    f16x8 v = *(const f16x8*)(H + m * DH + lane * 8);
    float d0 = 0.f, d1 = 0.f;
#pragma unroll
    for (int j = 0; j < 8; j++) {
        float hv = (float)v[j];
        int h = lane * 8 + j;
        d0 = fmaf(hv, WfS[h * 2], d0);
        d1 = fmaf(hv, WfS[h * 2 + 1], d1);
    }
#pragma unroll
    for (int off = 32; off; off >>= 1) {
        d0 += __shfl_down(d0, off);
        d1 += __shfl_down(d1, off);
    }
    if (lane == 0) {
        out[m * 2] = fmaf(d0, ACT_INV, bf_[0]);
        out[m * 2 + 1] = fmaf(d1, ACT_INV, bf_[1]);
    }
}

extern "C" void kernel_launch(void* const* d_in, const int* in_sizes, int n_in,
                              void* d_out, int out_size, void* d_ws, size_t ws_size,
                              hipStream_t stream) {
    (void)in_sizes; (void)n_in; (void)out_size; (void)ws_size;
    const float* x   = (const float*)d_in[0];
    const float* W0  = (const float*)d_in[1];
    const float* b0  = (const float*)d_in[2];
    const float* A   = (const float*)d_in[3];
    const float* Bw  = (const float*)d_in[4];
    const float* Cw  = (const float*)d_in[5];
    const float* Wf  = (const float*)d_in[6];
    const float* bfv = (const float*)d_in[7];
    float* out = (float*)d_out;

    char* ws = (char*)d_ws;
    size_t off = 0;
    auto alloc = [&](size_t bytes) {
        void* p = ws + off;
        off += (bytes + 255) & ~(size_t)255;
        return p;
    };
    f16* Bt = (f16*)alloc((size_t)3 * DH * DH * 2);
    f16* Ct = (f16*)alloc((size_t)3 * DH * DH * 2);
    f16* P  = (f16*)alloc((size_t)M_ROWS * DH * 2);  // layer activations
    f16* Q  = (f16*)alloc((size_t)M_ROWS * DH * 2);  // u / hs buffer
    float* finals  = (float*)alloc((size_t)NCH * NCHUNK * 4);

    dim3 b256(256);
    dim3 b512(512);
    dim3 ggrid(M_ROWS / 256, 2);
    prep_weights<<<dim3(16, 16, 6), dim3(32, 8), 0, stream>>>(Bw, Cw, Bt, Ct);
    dense0_kernel<<<M_ROWS * 64 / 256, b256, 0, stream>>>(x, W0, b0, P);
    for (int l = 0; l < 3; l++) {
        const float* Al = A + l * DH;
        gemm8<0><<<ggrid, b512, 0, stream>>>(P, Bt + (size_t)l * DH * DH, Q);
        scan_pass1<<<NCH * NCHUNK / 256, b256, 0, stream>>>(Q, Al, finals);
        scan_pass3<<<NCH * NCHUNK / 256, b256, 0, stream>>>(Q, Al, finals);
        gemm8<1><<<ggrid, b512, 0, stream>>>(Q, Ct + (size_t)l * DH * DH, P);
    }
    final_dense<<<M_ROWS / 4, b256, 0, stream>>>(P, Wf, bfv, out);
}